// Round 12
// baseline (943.476 us; speedup 1.0000x reference)
//
#include <hip/hip_runtime.h>
#include <hip/hip_fp16.h>

#define NN 8192
#define MM 8192
#define FD 128
#define EDm 128
#define HD 64
#define NH 4
#define NTILE 32

typedef float f32x4 __attribute__((ext_vector_type(4)));
typedef _Float16 h16x8 __attribute__((ext_vector_type(8)));
typedef unsigned int u32;
typedef u32 u32x4 __attribute__((ext_vector_type(4)));

// Fused: per-block recompute of vf[h][f] = Wf[h][f][:].a[h][:], then
// esrc[h][n] = F0[n,:] . vf[h,:]
__global__ void k_esrc(const float* __restrict__ F0, const float* __restrict__ Wf,
                       const float* __restrict__ a, float* __restrict__ esrc) {
  __shared__ float vfL[NH * FD];
  int t = threadIdx.x;  // 256
#pragma unroll
  for (int r = 0; r < 2; ++r) {
    int idx = t + r * 256;            // 512 entries
    int h = idx >> 7, f = idx & 127;
    const float* w = Wf + (size_t)(h * FD + f) * HD;
    const float* av = a + h * HD;
    float s = 0.f;
#pragma unroll
    for (int d = 0; d < HD; ++d) s += w[d] * av[d];
    vfL[idx] = s;
  }
  __syncthreads();
  int g = blockIdx.x * 256 + t;       // 32768
  int n = g >> 2, h = g & 3;
  const float4* fr = (const float4*)(F0 + (size_t)n * FD);
  const float4* vr = (const float4*)(vfL + h * FD);
  float s = 0.f;
#pragma unroll
  for (int i = 0; i < FD / 4; ++i) {
    float4 x = fr[i], y = vr[i];
    s += x.x * y.x + x.y * y.y + x.z * y.z + x.w * y.w;
  }
  esrc[h * NN + n] = s;
}

// E1 = E0·We per head; writes Bp (single copy) in MFMA-B fragment order
// (wave = 8 m-rows, lane = d), plus ed/ed2 fp16 exp tables.
__global__ void k_e1(const float* __restrict__ E0, const float* __restrict__ We,
                     const float* __restrict__ a, u32x4* __restrict__ Bp,
                     _Float16* __restrict__ edh, _Float16* __restrict__ ed2h) {
  int wid = (blockIdx.x * blockDim.x + threadIdx.x) >> 6;  // 4096 waves
  int lane = threadIdx.x & 63;
  int h = wid >> 10;
  int mg = wid & 1023;
  int m = mg * 8;
  const float* we = We + (size_t)h * EDm * HD + lane;
  const float* e0r = E0 + (size_t)m * EDm;
  float ac[8] = {};
#pragma unroll 4
  for (int e = 0; e < EDm; ++e) {
    float wv = we[e * HD];
#pragma unroll
    for (int j = 0; j < 8; ++j) ac[j] += e0r[j * EDm + e] * wv;
  }
  // Bp[h][mc][dt][quad*16+col]: 8 fp16 (m..m+7) at d = dt*16+col
  int mc = mg >> 2, quad = mg & 3, dt = lane >> 4, col = lane & 15;
  union { h16x8 v; u32x4 u; } hv;
#pragma unroll
  for (int j = 0; j < 8; ++j) hv.v[j] = (_Float16)ac[j];
  Bp[(((size_t)h * 256 + mc) * 4 + dt) * 64 + quad * 16 + col] = hv.u;

  float av = a[h * HD + lane];
  float d[8];
#pragma unroll
  for (int j = 0; j < 8; ++j) d[j] = ac[j] * av;
#pragma unroll
  for (int o = 32; o; o >>= 1)
#pragma unroll
    for (int j = 0; j < 8; ++j) d[j] += __shfl_xor(d[j], o);
  if (lane == 0) {
    const float L2E = 1.4426950408889634f;
    union { h16x8 v; u32x4 u; } e1, e2;
#pragma unroll
    for (int j = 0; j < 8; ++j) {
      e1.v[j] = (_Float16)exp2f(d[j] * L2E);
      e2.v[j] = (_Float16)exp2f(0.2f * d[j] * L2E);
    }
    *(u32x4*)(edh + (size_t)h * MM + m) = e1.u;
    *(u32x4*)(ed2h + (size_t)h * MM + m) = e2.u;
  }
}

// bit b0 at `bit`, b1 at bit+1 -> (b0?0xffff:0)|(b1?0xffff0000:0)
__device__ __forceinline__ u32 hm2b(u32 w, int bit) {
  return (((w >> bit) & 1u) | (((w >> (bit + 1)) & 1u) << 16)) * 0xffffu;
}

// Main: 256 blocks x 1024 thr. Phase 0: block ballots its own 32 A-rows into
// LDS bit-words. Then barrier-free MFMA loop with a 3-deep register pipeline
// (stage s holds raw aw/ed/e2/B for iter it; prefetch it+3 after consuming) —
// covers ~900-cycle first-touch latency on the cold Bp/ed streams.
__global__ __launch_bounds__(1024) void k_main(
    const int* __restrict__ A, const u32x4* __restrict__ Bp,
    const float* __restrict__ esrc, const _Float16* __restrict__ edh,
    const _Float16* __restrict__ ed2h, float* __restrict__ out) {
  __shared__ __align__(16) char smem[41472];
  u32* bits = (u32*)smem;              // [32 rows][257 words] (256 used)
  float* Hsum = (float*)smem;          // epilogue alias: [4][32][64] 32 KB
  float* Dsum = (float*)(smem + 32768);// [4][32]
  float* hp = (float*)(smem + 33280);  // [32][64]

  const int t = threadIdx.x;
  const int lane = t & 63;
  const int wv = t >> 6;       // 0..15
  const int h = wv & 3;        // head
  const int q = wv >> 2;       // m-quarter (2048 m)
  const int col = lane & 15;
  const int quad = lane >> 4;
  const int qs = quad * 8;
  const int n0 = blockIdx.x * NTILE;
  const float L2E = 1.4426950408889634f;

  // ---- phase 0: ballot 2 rows per wave into LDS bits ----
  {
    const int r0 = wv * 2, r1 = r0 + 1;
    const int* a0p = A + (size_t)(n0 + r0) * MM + lane;
    const int* a1p = A + (size_t)(n0 + r1) * MM + lane;
    for (int c8 = 0; c8 < 16; ++c8) {
      int v0[8], v1[8];
#pragma unroll
      for (int k = 0; k < 8; ++k)
        v0[k] = __builtin_nontemporal_load(a0p + (c8 * 8 + k) * 64);
#pragma unroll
      for (int k = 0; k < 8; ++k)
        v1[k] = __builtin_nontemporal_load(a1p + (c8 * 8 + k) * 64);
#pragma unroll
      for (int k = 0; k < 8; ++k) {
        int c = c8 * 8 + k;
        unsigned long long b = __ballot(v0[k] > 0);
        if (lane == 0) bits[r0 * 257 + 2 * c] = (u32)b;
        if (lane == 32) bits[r0 * 257 + 2 * c + 1] = (u32)(b >> 32);
      }
#pragma unroll
      for (int k = 0; k < 8; ++k) {
        int c = c8 * 8 + k;
        unsigned long long b = __ballot(v1[k] > 0);
        if (lane == 0) bits[r1 * 257 + 2 * c] = (u32)b;
        if (lane == 32) bits[r1 * 257 + 2 * c + 1] = (u32)(b >> 32);
      }
    }
  }
  __syncthreads();

  // ---- main loop ----
  float s0 = esrc[h * NN + n0 + col];
  float s1 = esrc[h * NN + n0 + 16 + col];
  _Float16 e80 = (_Float16)exp2f(0.8f * s0 * L2E);
  _Float16 e81 = (_Float16)exp2f(0.8f * s1 * L2E);
  h16x8 es80 = {e80, e80, e80, e80, e80, e80, e80, e80};
  h16x8 es81 = {e81, e81, e81, e81, e81, e81, e81, e81};

  f32x4 acc[2][4] = {};
  f32x4 accd[2] = {};
  const h16x8 ones = {(_Float16)1.f, (_Float16)1.f, (_Float16)1.f, (_Float16)1.f,
                      (_Float16)1.f, (_Float16)1.f, (_Float16)1.f, (_Float16)1.f};

  const u32* w0p = bits + col * 257 + q * 64;          // +it
  const u32* w1p = bits + (col + 16) * 257 + q * 64;   // +it
  const _Float16* edp = edh + (size_t)h * MM + q * 2048 + qs;   // +it*32
  const _Float16* e2p = ed2h + (size_t)h * MM + q * 2048 + qs;
  const u32x4* bp = Bp + ((size_t)h * 256 + q * 64) * 256 + lane; // +it*256+dt*64

  // 3-deep pipeline stage registers
  u32 saw0[3], saw1[3];
  h16x8 sed[3], se2[3];
  u32x4 sb0[3], sb1[3], sb2[3], sb3[3];

#define PRELOAD(S, ITV)                                                        \
  {                                                                            \
    saw0[S] = w0p[ITV];                                                        \
    saw1[S] = w1p[ITV];                                                        \
    sed[S] = *(const h16x8*)(edp + (ITV) * 32);                                \
    se2[S] = *(const h16x8*)(e2p + (ITV) * 32);                                \
    sb0[S] = bp[(ITV) * 256];                                                  \
    sb1[S] = bp[(ITV) * 256 + 64];                                             \
    sb2[S] = bp[(ITV) * 256 + 128];                                            \
    sb3[S] = bp[(ITV) * 256 + 192];                                            \
  }

#define BODY(S, ITV, PF)                                                       \
  {                                                                            \
    u32x4 m0, m1;                                                              \
    m0.x = hm2b(saw0[S], qs);     m0.y = hm2b(saw0[S], qs + 2);                \
    m0.z = hm2b(saw0[S], qs + 4); m0.w = hm2b(saw0[S], qs + 6);                \
    m1.x = hm2b(saw1[S], qs);     m1.y = hm2b(saw1[S], qs + 2);                \
    m1.z = hm2b(saw1[S], qs + 4); m1.w = hm2b(saw1[S], qs + 6);                \
    union { h16x8 v; u32x4 u; } w0, w1, b0, b1, b2, b3;                        \
    b0.u = sb0[S]; b1.u = sb1[S]; b2.u = sb2[S]; b3.u = sb3[S];                \
    w0.v = __builtin_elementwise_max(sed[S] * es80, se2[S]);                   \
    w1.v = __builtin_elementwise_max(sed[S] * es81, se2[S]);                   \
    w0.u &= m0;                                                                \
    w1.u &= m1;                                                                \
    acc[0][0] = __builtin_amdgcn_mfma_f32_16x16x32_f16(w0.v, b0.v, acc[0][0], 0, 0, 0); \
    acc[1][0] = __builtin_amdgcn_mfma_f32_16x16x32_f16(w1.v, b0.v, acc[1][0], 0, 0, 0); \
    acc[0][1] = __builtin_amdgcn_mfma_f32_16x16x32_f16(w0.v, b1.v, acc[0][1], 0, 0, 0); \
    acc[1][1] = __builtin_amdgcn_mfma_f32_16x16x32_f16(w1.v, b1.v, acc[1][1], 0, 0, 0); \
    acc[0][2] = __builtin_amdgcn_mfma_f32_16x16x32_f16(w0.v, b2.v, acc[0][2], 0, 0, 0); \
    acc[1][2] = __builtin_amdgcn_mfma_f32_16x16x32_f16(w1.v, b2.v, acc[1][2], 0, 0, 0); \
    acc[0][3] = __builtin_amdgcn_mfma_f32_16x16x32_f16(w0.v, b3.v, acc[0][3], 0, 0, 0); \
    acc[1][3] = __builtin_amdgcn_mfma_f32_16x16x32_f16(w1.v, b3.v, acc[1][3], 0, 0, 0); \
    accd[0] = __builtin_amdgcn_mfma_f32_16x16x32_f16(w0.v, ones, accd[0], 0, 0, 0);     \
    accd[1] = __builtin_amdgcn_mfma_f32_16x16x32_f16(w1.v, ones, accd[1], 0, 0, 0);     \
    if (PF) PRELOAD(S, (ITV) + 3)                                              \
  }

  PRELOAD(0, 0)
  PRELOAD(1, 1)
  PRELOAD(2, 2)

  for (int itb = 0; itb < 63; itb += 3) {
    BODY(0, itb, itb + 3 < 64)
    BODY(1, itb + 1, itb + 4 < 64)
    BODY(2, itb + 2, itb + 5 < 64)
  }
  BODY(0, 63, 0)   // 63 % 3 == 0
#undef BODY
#undef PRELOAD
  __syncthreads();   // bits dead; re-purpose LDS for reduction

  for (int i = t; i < 8320; i += 1024) Hsum[i] = 0.f;  // Hsum + Dsum
  __syncthreads();

  float* Hh = Hsum + h * 2048;
#pragma unroll
  for (int rt = 0; rt < 2; ++rt) {
#pragma unroll
    for (int dt = 0; dt < 4; ++dt)
#pragma unroll
      for (int r2 = 0; r2 < 4; ++r2)
        atomicAdd(&Hh[(rt * 16 + quad * 4 + r2) * 64 + dt * 16 + col],
                  acc[rt][dt][r2]);
    if (col == 0) {
#pragma unroll
      for (int r2 = 0; r2 < 4; ++r2)
        atomicAdd(&Dsum[h * 32 + rt * 16 + quad * 4 + r2], accd[rt][r2]);
    }
  }
  __syncthreads();

  for (int i = t; i < 2048; i += 1024) {
    int r = i >> 6;
    float v = 0.f;
#pragma unroll
    for (int hh = 0; hh < 4; ++hh) v += Hsum[hh * 2048 + i] / Dsum[hh * 32 + r];
    hp[i] = 0.25f * v;
  }
  __syncthreads();

#pragma unroll
  for (int i = 0; i < 2; ++i) {
    int r = wv * 2 + i;
    float v = hp[r * 64 + lane];
    float mx = v;
#pragma unroll
    for (int o = 32; o; o >>= 1) mx = fmaxf(mx, __shfl_xor(mx, o));
    float p = exp2f((v - mx) * L2E);
    float sm = p;
#pragma unroll
    for (int o = 32; o; o >>= 1) sm += __shfl_xor(sm, o);
    out[(size_t)(n0 + r) * HD + lane] = p / sm;
  }
}

extern "C" void kernel_launch(void* const* d_in, const int* in_sizes, int n_in,
                              void* d_out, int out_size, void* d_ws, size_t ws_size,
                              hipStream_t stream) {
  const float* F0 = (const float*)d_in[0];
  const float* E0 = (const float*)d_in[1];
  const int* A = (const int*)d_in[2];
  const float* Wf = (const float*)d_in[3];
  const float* We = (const float*)d_in[4];
  const float* a = (const float*)d_in[5];
  float* out = (float*)d_out;

  char* w = (char*)d_ws;
  float* esrc = (float*)w;        w += (size_t)NH * NN * 4;
  _Float16* edh = (_Float16*)w;   w += (size_t)NH * MM * 2;
  _Float16* ed2h = (_Float16*)w;  w += (size_t)NH * MM * 2;
  u32x4* Bp = (u32x4*)w;          w += (size_t)NH * HD * MM * 2;

  k_esrc<<<(NH * NN) / 256 / 4, 256, 0, stream>>>(F0, Wf, a, esrc);
  k_e1<<<(NH * MM / 8) / 4, 256, 0, stream>>>(E0, We, a, Bp, edh, ed2h);
  k_main<<<NN / NTILE, 1024, 0, stream>>>(A, Bp, esrc, edh, ed2h, out);
}

// Round 13
// 490.426 us; speedup vs baseline: 1.9238x; 1.9238x over previous
//
#include <hip/hip_runtime.h>
#include <hip/hip_fp16.h>

#define NN 8192
#define MM 8192
#define FD 128
#define EDm 128
#define HD 64
#define NH 4
#define NTILE 32

typedef float f32x4 __attribute__((ext_vector_type(4)));
typedef _Float16 h16x8 __attribute__((ext_vector_type(8)));
typedef unsigned int u32;
typedef u32 u32x4 __attribute__((ext_vector_type(4)));

// Fused: per-block recompute of vf[h][f] = Wf[h][f][:].a[h][:], then
// esrc[h][n] = F0[n,:] . vf[h,:]
__global__ void k_esrc(const float* __restrict__ F0, const float* __restrict__ Wf,
                       const float* __restrict__ a, float* __restrict__ esrc) {
  __shared__ float vfL[NH * FD];
  int t = threadIdx.x;  // 256
#pragma unroll
  for (int r = 0; r < 2; ++r) {
    int idx = t + r * 256;            // 512 entries
    int h = idx >> 7, f = idx & 127;
    const float* w = Wf + (size_t)(h * FD + f) * HD;
    const float* av = a + h * HD;
    float s = 0.f;
#pragma unroll
    for (int d = 0; d < HD; ++d) s += w[d] * av[d];
    vfL[idx] = s;
  }
  __syncthreads();
  int g = blockIdx.x * 256 + t;       // 32768
  int n = g >> 2, h = g & 3;
  const float4* fr = (const float4*)(F0 + (size_t)n * FD);
  const float4* vr = (const float4*)(vfL + h * FD);
  float s = 0.f;
#pragma unroll
  for (int i = 0; i < FD / 4; ++i) {
    float4 x = fr[i], y = vr[i];
    s += x.x * y.x + x.y * y.y + x.z * y.z + x.w * y.w;
  }
  esrc[h * NN + n] = s;
}

// E1 = E0·We per head; writes Bp (single copy) in MFMA-B fragment order
// (wave = 8 m-rows, lane = d), plus ed/ed2 fp16 exp tables.
__global__ void k_e1(const float* __restrict__ E0, const float* __restrict__ We,
                     const float* __restrict__ a, u32x4* __restrict__ Bp,
                     _Float16* __restrict__ edh, _Float16* __restrict__ ed2h) {
  int wid = (blockIdx.x * blockDim.x + threadIdx.x) >> 6;  // 4096 waves
  int lane = threadIdx.x & 63;
  int h = wid >> 10;
  int mg = wid & 1023;
  int m = mg * 8;
  const float* we = We + (size_t)h * EDm * HD + lane;
  const float* e0r = E0 + (size_t)m * EDm;
  float ac[8] = {};
#pragma unroll 4
  for (int e = 0; e < EDm; ++e) {
    float wv = we[e * HD];
#pragma unroll
    for (int j = 0; j < 8; ++j) ac[j] += e0r[j * EDm + e] * wv;
  }
  // Bp[h][mc][dt][quad*16+col]: 8 fp16 (m..m+7) at d = dt*16+col
  int mc = mg >> 2, quad = mg & 3, dt = lane >> 4, col = lane & 15;
  union { h16x8 v; u32x4 u; } hv;
#pragma unroll
  for (int j = 0; j < 8; ++j) hv.v[j] = (_Float16)ac[j];
  Bp[(((size_t)h * 256 + mc) * 4 + dt) * 64 + quad * 16 + col] = hv.u;

  float av = a[h * HD + lane];
  float d[8];
#pragma unroll
  for (int j = 0; j < 8; ++j) d[j] = ac[j] * av;
#pragma unroll
  for (int o = 32; o; o >>= 1)
#pragma unroll
    for (int j = 0; j < 8; ++j) d[j] += __shfl_xor(d[j], o);
  if (lane == 0) {
    const float L2E = 1.4426950408889634f;
    union { h16x8 v; u32x4 u; } e1, e2;
#pragma unroll
    for (int j = 0; j < 8; ++j) {
      e1.v[j] = (_Float16)exp2f(d[j] * L2E);
      e2.v[j] = (_Float16)exp2f(0.2f * d[j] * L2E);
    }
    *(u32x4*)(edh + (size_t)h * MM + m) = e1.u;
    *(u32x4*)(ed2h + (size_t)h * MM + m) = e2.u;
  }
}

// bit b0 at `bit`, b1 at bit+1 -> (b0?0xffff:0)|(b1?0xffff0000:0)
__device__ __forceinline__ u32 hm2b(u32 w, int bit) {
  return (((w >> bit) & 1u) | (((w >> (bit + 1)) & 1u) << 16)) * 0xffffu;
}

// Main: 256 blocks x 1024 thr. Phase 0: block ballots its own 32 A-rows into
// LDS bit-words. Then barrier-free MFMA loop with a 2-deep register pipeline
// — sized to the 128-VGPR cap of 1024-thread blocks (R12's 3-deep spilled).
__global__ __launch_bounds__(1024, 4) void k_main(
    const int* __restrict__ A, const u32x4* __restrict__ Bp,
    const float* __restrict__ esrc, const _Float16* __restrict__ edh,
    const _Float16* __restrict__ ed2h, float* __restrict__ out) {
  __shared__ __align__(16) char smem[41472];
  u32* bits = (u32*)smem;              // [32 rows][257 words] (256 used)
  float* Hsum = (float*)smem;          // epilogue alias: [4][32][64] 32 KB
  float* Dsum = (float*)(smem + 32768);// [4][32]
  float* hp = (float*)(smem + 33280);  // [32][64]

  const int t = threadIdx.x;
  const int lane = t & 63;
  const int wv = t >> 6;       // 0..15
  const int h = wv & 3;        // head
  const int q = wv >> 2;       // m-quarter (2048 m)
  const int col = lane & 15;
  const int quad = lane >> 4;
  const int qs = quad * 8;
  const int n0 = blockIdx.x * NTILE;
  const float L2E = 1.4426950408889634f;

  // ---- phase 0: ballot 2 rows per wave into LDS bits ----
  {
    const int r0 = wv * 2, r1 = r0 + 1;
    const int* a0p = A + (size_t)(n0 + r0) * MM + lane;
    const int* a1p = A + (size_t)(n0 + r1) * MM + lane;
    for (int c8 = 0; c8 < 16; ++c8) {
      int v0[8], v1[8];
#pragma unroll
      for (int k = 0; k < 8; ++k)
        v0[k] = __builtin_nontemporal_load(a0p + (c8 * 8 + k) * 64);
#pragma unroll
      for (int k = 0; k < 8; ++k)
        v1[k] = __builtin_nontemporal_load(a1p + (c8 * 8 + k) * 64);
#pragma unroll
      for (int k = 0; k < 8; ++k) {
        int c = c8 * 8 + k;
        unsigned long long b = __ballot(v0[k] > 0);
        if (lane == 0) bits[r0 * 257 + 2 * c] = (u32)b;
        if (lane == 32) bits[r0 * 257 + 2 * c + 1] = (u32)(b >> 32);
      }
#pragma unroll
      for (int k = 0; k < 8; ++k) {
        int c = c8 * 8 + k;
        unsigned long long b = __ballot(v1[k] > 0);
        if (lane == 0) bits[r1 * 257 + 2 * c] = (u32)b;
        if (lane == 32) bits[r1 * 257 + 2 * c + 1] = (u32)(b >> 32);
      }
    }
  }
  __syncthreads();

  // ---- main loop ----
  float s0 = esrc[h * NN + n0 + col];
  float s1 = esrc[h * NN + n0 + 16 + col];
  _Float16 e80 = (_Float16)exp2f(0.8f * s0 * L2E);
  _Float16 e81 = (_Float16)exp2f(0.8f * s1 * L2E);
  h16x8 es80 = {e80, e80, e80, e80, e80, e80, e80, e80};
  h16x8 es81 = {e81, e81, e81, e81, e81, e81, e81, e81};

  f32x4 acc[2][4] = {};
  f32x4 accd[2] = {};
  const h16x8 ones = {(_Float16)1.f, (_Float16)1.f, (_Float16)1.f, (_Float16)1.f,
                      (_Float16)1.f, (_Float16)1.f, (_Float16)1.f, (_Float16)1.f};

  const u32* w0p = bits + col * 257 + q * 64;          // +it
  const u32* w1p = bits + (col + 16) * 257 + q * 64;   // +it
  const _Float16* edp = edh + (size_t)h * MM + q * 2048 + qs;   // +it*32
  const _Float16* e2p = ed2h + (size_t)h * MM + q * 2048 + qs;
  const u32x4* bp = Bp + ((size_t)h * 256 + q * 64) * 256 + lane; // +it*256+dt*64

  // 2-deep pipeline stage registers
  u32 saw0[2], saw1[2];
  h16x8 sed[2], se2[2];
  u32x4 sb0[2], sb1[2], sb2[2], sb3[2];

#define PRELOAD(S, ITV)                                                        \
  {                                                                            \
    saw0[S] = w0p[ITV];                                                        \
    saw1[S] = w1p[ITV];                                                        \
    sed[S] = *(const h16x8*)(edp + (ITV) * 32);                                \
    se2[S] = *(const h16x8*)(e2p + (ITV) * 32);                                \
    sb0[S] = bp[(ITV) * 256];                                                  \
    sb1[S] = bp[(ITV) * 256 + 64];                                             \
    sb2[S] = bp[(ITV) * 256 + 128];                                            \
    sb3[S] = bp[(ITV) * 256 + 192];                                            \
  }

#define BODY(S, ITV, PF)                                                       \
  {                                                                            \
    u32x4 m0, m1;                                                              \
    m0.x = hm2b(saw0[S], qs);     m0.y = hm2b(saw0[S], qs + 2);                \
    m0.z = hm2b(saw0[S], qs + 4); m0.w = hm2b(saw0[S], qs + 6);                \
    m1.x = hm2b(saw1[S], qs);     m1.y = hm2b(saw1[S], qs + 2);                \
    m1.z = hm2b(saw1[S], qs + 4); m1.w = hm2b(saw1[S], qs + 6);                \
    union { h16x8 v; u32x4 u; } w0, w1, b0, b1, b2, b3;                        \
    b0.u = sb0[S]; b1.u = sb1[S]; b2.u = sb2[S]; b3.u = sb3[S];                \
    w0.v = __builtin_elementwise_max(sed[S] * es80, se2[S]);                   \
    w1.v = __builtin_elementwise_max(sed[S] * es81, se2[S]);                   \
    w0.u &= m0;                                                                \
    w1.u &= m1;                                                                \
    acc[0][0] = __builtin_amdgcn_mfma_f32_16x16x32_f16(w0.v, b0.v, acc[0][0], 0, 0, 0); \
    acc[1][0] = __builtin_amdgcn_mfma_f32_16x16x32_f16(w1.v, b0.v, acc[1][0], 0, 0, 0); \
    acc[0][1] = __builtin_amdgcn_mfma_f32_16x16x32_f16(w0.v, b1.v, acc[0][1], 0, 0, 0); \
    acc[1][1] = __builtin_amdgcn_mfma_f32_16x16x32_f16(w1.v, b1.v, acc[1][1], 0, 0, 0); \
    acc[0][2] = __builtin_amdgcn_mfma_f32_16x16x32_f16(w0.v, b2.v, acc[0][2], 0, 0, 0); \
    acc[1][2] = __builtin_amdgcn_mfma_f32_16x16x32_f16(w1.v, b2.v, acc[1][2], 0, 0, 0); \
    acc[0][3] = __builtin_amdgcn_mfma_f32_16x16x32_f16(w0.v, b3.v, acc[0][3], 0, 0, 0); \
    acc[1][3] = __builtin_amdgcn_mfma_f32_16x16x32_f16(w1.v, b3.v, acc[1][3], 0, 0, 0); \
    accd[0] = __builtin_amdgcn_mfma_f32_16x16x32_f16(w0.v, ones, accd[0], 0, 0, 0);     \
    accd[1] = __builtin_amdgcn_mfma_f32_16x16x32_f16(w1.v, ones, accd[1], 0, 0, 0);     \
    if (PF) PRELOAD(S, (ITV) + 2)                                              \
  }

  PRELOAD(0, 0)
  PRELOAD(1, 1)

  for (int itb = 0; itb < 62; itb += 2) {
    BODY(0, itb, 1)
    BODY(1, itb + 1, 1)
  }
  BODY(0, 62, 0)
  BODY(1, 63, 0)
#undef BODY
#undef PRELOAD
  __syncthreads();   // bits dead; re-purpose LDS for reduction

  for (int i = t; i < 8320; i += 1024) Hsum[i] = 0.f;  // Hsum + Dsum
  __syncthreads();

  float* Hh = Hsum + h * 2048;
#pragma unroll
  for (int rt = 0; rt < 2; ++rt) {
#pragma unroll
    for (int dt = 0; dt < 4; ++dt)
#pragma unroll
      for (int r2 = 0; r2 < 4; ++r2)
        atomicAdd(&Hh[(rt * 16 + quad * 4 + r2) * 64 + dt * 16 + col],
                  acc[rt][dt][r2]);
    if (col == 0) {
#pragma unroll
      for (int r2 = 0; r2 < 4; ++r2)
        atomicAdd(&Dsum[h * 32 + rt * 16 + quad * 4 + r2], accd[rt][r2]);
    }
  }
  __syncthreads();

  for (int i = t; i < 2048; i += 1024) {
    int r = i >> 6;
    float v = 0.f;
#pragma unroll
    for (int hh = 0; hh < 4; ++hh) v += Hsum[hh * 2048 + i] / Dsum[hh * 32 + r];
    hp[i] = 0.25f * v;
  }
  __syncthreads();

#pragma unroll
  for (int i = 0; i < 2; ++i) {
    int r = wv * 2 + i;
    float v = hp[r * 64 + lane];
    float mx = v;
#pragma unroll
    for (int o = 32; o; o >>= 1) mx = fmaxf(mx, __shfl_xor(mx, o));
    float p = exp2f((v - mx) * L2E);
    float sm = p;
#pragma unroll
    for (int o = 32; o; o >>= 1) sm += __shfl_xor(sm, o);
    out[(size_t)(n0 + r) * HD + lane] = p / sm;
  }
}

extern "C" void kernel_launch(void* const* d_in, const int* in_sizes, int n_in,
                              void* d_out, int out_size, void* d_ws, size_t ws_size,
                              hipStream_t stream) {
  const float* F0 = (const float*)d_in[0];
  const float* E0 = (const float*)d_in[1];
  const int* A = (const int*)d_in[2];
  const float* Wf = (const float*)d_in[3];
  const float* We = (const float*)d_in[4];
  const float* a = (const float*)d_in[5];
  float* out = (float*)d_out;

  char* w = (char*)d_ws;
  float* esrc = (float*)w;        w += (size_t)NH * NN * 4;
  _Float16* edh = (_Float16*)w;   w += (size_t)NH * MM * 2;
  _Float16* ed2h = (_Float16*)w;  w += (size_t)NH * MM * 2;
  u32x4* Bp = (u32x4*)w;          w += (size_t)NH * HD * MM * 2;

  k_esrc<<<(NH * NN) / 256 / 4, 256, 0, stream>>>(F0, Wf, a, esrc);
  k_e1<<<(NH * MM / 8) / 4, 256, 0, stream>>>(E0, We, a, Bp, edh, ed2h);
  k_main<<<NN / NTILE, 1024, 0, stream>>>(A, Bp, esrc, edh, ed2h, out);
}